// Round 9
// baseline (137.182 us; speedup 1.0000x reference)
//
#include <hip/hip_runtime.h>

#define NN 32768
#define KK 32
#define DD 128

typedef float v2f __attribute__((ext_vector_type(2)));
typedef float v4f __attribute__((ext_vector_type(4)));

// ---------------------------------------------------------------------------
// Prep kernel: x8[r,:] = fp8_e4m3(x[r,:]) (128 B/row, per-branch table = 4 MiB)
//              xw[r]   = dot(x[r,:], w)   (fp32, exact op path)
// ---------------------------------------------------------------------------
__global__ __launch_bounds__(256) void prep_kernel(const float* __restrict__ x1,
                                                   const float* __restrict__ x2,
                                                   const float* __restrict__ w,
                                                   unsigned int* __restrict__ x8,
                                                   float* __restrict__ xw) {
    const int wave = threadIdx.x >> 6;
    const int lane = threadIdx.x & 63;
    const int half = lane >> 5;
    const int c    = lane & 31;
    const int row  = blockIdx.x * 8 + wave * 2 + half;   // 0..2N-1
    const float* x = (row < NN) ? (x1 + (size_t)row * DD)
                                : (x2 + (size_t)(row - NN) * DD);
    const float4 xv = *(const float4*)(x + 4 * c);
    const float4 wv = *(const float4*)(w + 4 * c);

    int packed = __builtin_amdgcn_cvt_pk_fp8_f32(xv.x, xv.y, 0, false);
    packed     = __builtin_amdgcn_cvt_pk_fp8_f32(xv.z, xv.w, packed, true);
    x8[(size_t)row * 32 + c] = (unsigned int)packed;

    float s = xv.x * wv.x + xv.y * wv.y + xv.z * wv.z + xv.w * wv.w;
    #pragma unroll
    for (int m = 16; m >= 1; m >>= 1)
        s += __shfl_xor(s, m, 64);
    if (c == 0) xw[row] = s;
}

// ---------------------------------------------------------------------------
// Main kernel. 256 threads = 16 n-rows (16 lanes/row, 8 fp8/lane per gather).
// Gather is software-pipelined with inline asm: each steady-state block
// issues 8 global_load_dwordx2 (saddr + 32-bit voffset) then s_waitcnt
// vmcnt(8) -> previous batch complete, new batch in flight. ALL load
// destinations are EARLY-CLOBBER (=&v): round-8's crash was dest/address
// register aliasing without it.
// ---------------------------------------------------------------------------
__global__ __launch_bounds__(256) void pgnn_main(
    const uint2* __restrict__ x8,   // [2N, 16] uint2 = 8 fp8 each
    const float* __restrict__ xw,   // [2N]
    const int* __restrict__ idx1, const float* __restrict__ dm1,
    const int* __restrict__ idx2, const float* __restrict__ dm2,
    const float* __restrict__ b_out,
    float* __restrict__ out)
{
    // grid.x = 2 * NN/16 = 4096. xcd = blockIdx%8; xcd 0-3 -> branch 0.
    const int g      = blockIdx.x;
    const int xcd    = g & 7;
    const int branch = xcd >> 2;
    const int nb     = (g >> 3) * 4 + (xcd & 3);     // [0, NN/16)

    const uint2* __restrict__ xb  = x8 + (size_t)branch * NN * 16;
    const float* __restrict__ xwb = xw + (size_t)branch * NN;
    const int*   __restrict__ idx = branch ? idx2 : idx1;
    const float* __restrict__ dm  = branch ? dm2  : dm1;
    float* __restrict__ op = out + (size_t)branch * ((size_t)NN * KK + (size_t)NN * DD);
    float* __restrict__ os = op + (size_t)NN * KK;

    __shared__ uint2 s_pair[16][KK + 2];  // .x = row idx, .y = dm bits

    const int tid = threadIdx.x;
    const int n0  = nb * 16;

    // Stage (idx,dm) and emit op. idx/dm streamed once -> nontemporal.
    const float bb = b_out[0];
    #pragma unroll
    for (int j = tid; j < 16 * KK; j += 256) {
        const int rr = j >> 5;
        const int k  = j & 31;
        const size_t off = (size_t)(n0 + rr) * KK + k;
        const int   i  = __builtin_nontemporal_load(idx + off);
        const float dv = __builtin_nontemporal_load(dm + off);
        s_pair[rr][k] = make_uint2((unsigned)i, __float_as_uint(dv));
        __builtin_nontemporal_store(dv * xwb[i] + bb, &op[off]);
    }
    __syncthreads();

    const int sub = tid >> 4;    // n-row within block: 0..15
    const int h   = tid & 15;    // 8-byte chunk within the 128 B row
    const uint2* __restrict__ prow = s_pair[sub];
    const unsigned hoff = (unsigned)(h << 3);

    float a0=0.f,a1=0.f,a2=0.f,a3=0.f,a4=0.f,a5=0.f,a6=0.f,a7=0.f;
    uint2 ucur[8], unext[8];
    float dcur[8], dnext[8];

    // ---- prologue: offsets + issue batch 0 (no wait) ----
    unsigned off0[8];
    #pragma unroll
    for (int j = 0; j < 8; ++j) {
        const uint2 pr = prow[j];
        dcur[j] = __uint_as_float(pr.y);
        off0[j] = (pr.x << 7) | hoff;        // row*128 + h*8
    }
    asm volatile(
        "global_load_dwordx2 %0, %8, %16\n\t"
        "global_load_dwordx2 %1, %9, %16\n\t"
        "global_load_dwordx2 %2, %10, %16\n\t"
        "global_load_dwordx2 %3, %11, %16\n\t"
        "global_load_dwordx2 %4, %12, %16\n\t"
        "global_load_dwordx2 %5, %13, %16\n\t"
        "global_load_dwordx2 %6, %14, %16\n\t"
        "global_load_dwordx2 %7, %15, %16"
        : "=&v"(ucur[0]), "=&v"(ucur[1]), "=&v"(ucur[2]), "=&v"(ucur[3]),
          "=&v"(ucur[4]), "=&v"(ucur[5]), "=&v"(ucur[6]), "=&v"(ucur[7])
        : "v"(off0[0]), "v"(off0[1]), "v"(off0[2]), "v"(off0[3]),
          "v"(off0[4]), "v"(off0[5]), "v"(off0[6]), "v"(off0[7]),
          "s"(xb)
        : "memory");

    // ---- steady state: issue batch b, wait for batch b-1, consume ----
    #pragma unroll
    for (int b = 1; b < KK / 8; ++b) {
        unsigned offn[8];
        #pragma unroll
        for (int j = 0; j < 8; ++j) {
            const uint2 pr = prow[b * 8 + j];
            dnext[j] = __uint_as_float(pr.y);
            offn[j]  = (pr.x << 7) | hoff;
        }
        asm volatile(
            "global_load_dwordx2 %0, %16, %24\n\t"
            "global_load_dwordx2 %1, %17, %24\n\t"
            "global_load_dwordx2 %2, %18, %24\n\t"
            "global_load_dwordx2 %3, %19, %24\n\t"
            "global_load_dwordx2 %4, %20, %24\n\t"
            "global_load_dwordx2 %5, %21, %24\n\t"
            "global_load_dwordx2 %6, %22, %24\n\t"
            "global_load_dwordx2 %7, %23, %24\n\t"
            "s_waitcnt vmcnt(8)"
            : "=&v"(unext[0]), "=&v"(unext[1]), "=&v"(unext[2]), "=&v"(unext[3]),
              "=&v"(unext[4]), "=&v"(unext[5]), "=&v"(unext[6]), "=&v"(unext[7]),
              "+v"(ucur[0]), "+v"(ucur[1]), "+v"(ucur[2]), "+v"(ucur[3]),
              "+v"(ucur[4]), "+v"(ucur[5]), "+v"(ucur[6]), "+v"(ucur[7])
            : "v"(offn[0]), "v"(offn[1]), "v"(offn[2]), "v"(offn[3]),
              "v"(offn[4]), "v"(offn[5]), "v"(offn[6]), "v"(offn[7]),
              "s"(xb)
            : "memory");
        #pragma unroll
        for (int j = 0; j < 8; ++j) {
            const float d = dcur[j];
            const v2f f0 = __builtin_amdgcn_cvt_pk_f32_fp8((int)ucur[j].x, false);
            const v2f f1 = __builtin_amdgcn_cvt_pk_f32_fp8((int)ucur[j].x, true);
            const v2f f2 = __builtin_amdgcn_cvt_pk_f32_fp8((int)ucur[j].y, false);
            const v2f f3 = __builtin_amdgcn_cvt_pk_f32_fp8((int)ucur[j].y, true);
            a0 += d * f0.x; a1 += d * f0.y; a2 += d * f1.x; a3 += d * f1.y;
            a4 += d * f2.x; a5 += d * f2.y; a6 += d * f3.x; a7 += d * f3.y;
        }
        #pragma unroll
        for (int j = 0; j < 8; ++j) { ucur[j] = unext[j]; dcur[j] = dnext[j]; }
    }

    // ---- epilogue: wait for the last batch, consume ----
    asm volatile("s_waitcnt vmcnt(0)"
                 : "+v"(ucur[0]), "+v"(ucur[1]), "+v"(ucur[2]), "+v"(ucur[3]),
                   "+v"(ucur[4]), "+v"(ucur[5]), "+v"(ucur[6]), "+v"(ucur[7])
                 :
                 : "memory");
    #pragma unroll
    for (int j = 0; j < 8; ++j) {
        const float d = dcur[j];
        const v2f f0 = __builtin_amdgcn_cvt_pk_f32_fp8((int)ucur[j].x, false);
        const v2f f1 = __builtin_amdgcn_cvt_pk_f32_fp8((int)ucur[j].x, true);
        const v2f f2 = __builtin_amdgcn_cvt_pk_f32_fp8((int)ucur[j].y, false);
        const v2f f3 = __builtin_amdgcn_cvt_pk_f32_fp8((int)ucur[j].y, true);
        a0 += d * f0.x; a1 += d * f0.y; a2 += d * f1.x; a3 += d * f1.y;
        a4 += d * f2.x; a5 += d * f2.y; a6 += d * f3.x; a7 += d * f3.y;
    }

    const float inv = 1.0f / KK;
    v4f o0 = { a0 * inv, a1 * inv, a2 * inv, a3 * inv };
    v4f o1 = { a4 * inv, a5 * inv, a6 * inv, a7 * inv };
    float* dst = os + (size_t)(n0 + sub) * DD + h * 8;
    __builtin_nontemporal_store(o0, (v4f*)dst);
    __builtin_nontemporal_store(o1, (v4f*)(dst + 4));
}

// ---------------------------------------------------------------------------
// Fallback (ws too small): round-2 fused fp32 kernel, known-good at 124 us.
// ---------------------------------------------------------------------------
__global__ __launch_bounds__(256) void pgnn_fused(
    const float* __restrict__ x1, const int* __restrict__ idx1,
    const float* __restrict__ dm1,
    const float* __restrict__ x2, const int* __restrict__ idx2,
    const float* __restrict__ dm2,
    const float* __restrict__ w, const float* __restrict__ b_out,
    float* __restrict__ out)
{
    const int branch = blockIdx.y;
    const float* __restrict__ x   = branch ? x2   : x1;
    const int*   __restrict__ idx = branch ? idx2 : idx1;
    const float* __restrict__ dm  = branch ? dm2  : dm1;
    float* __restrict__ op = out + (size_t)branch * ((size_t)NN * KK + (size_t)NN * DD);
    float* __restrict__ os = op + (size_t)NN * KK;

    __shared__ int    s_idx[2][KK];
    __shared__ float  s_dm [2][KK];
    __shared__ float  s_dot[2][KK];
    __shared__ float4 s_acc[2][128];

    const int sub = threadIdx.x >> 7;
    const int t   = threadIdx.x & 127;
    const int gg  = t >> 5;
    const int c   = t & 31;
    const int n   = blockIdx.x * 2 + sub;

    if (t < KK) {
        s_idx[sub][t] = idx[(size_t)n * KK + t];
        s_dm [sub][t] = dm [(size_t)n * KK + t];
    }
    const float4 wv = *(const float4*)(w + 4 * c);
    __syncthreads();

    float4 acc = make_float4(0.f, 0.f, 0.f, 0.f);
    #pragma unroll
    for (int k0 = 0; k0 < KK / 4; ++k0) {
        const int   kk  = k0 * 4 + gg;
        const int   r   = s_idx[sub][kk];
        const float dmk = s_dm [sub][kk];
        const float4 v  = *(const float4*)(x + (size_t)r * DD + 4 * c);
        acc.x += dmk * v.x; acc.y += dmk * v.y;
        acc.z += dmk * v.z; acc.w += dmk * v.w;
        float p = v.x * wv.x + v.y * wv.y + v.z * wv.z + v.w * wv.w;
        #pragma unroll
        for (int m = 16; m >= 1; m >>= 1)
            p += __shfl_xor(p, m, 64);
        if (c == 0) s_dot[sub][kk] = p;
    }
    s_acc[sub][t] = acc;
    __syncthreads();

    if (t < KK)
        op[(size_t)n * KK + t] = s_dm[sub][t] * s_dot[sub][t] + b_out[0];
    if (t < 32) {
        const float4 b0 = s_acc[sub][t];
        const float4 b1 = s_acc[sub][32 + t];
        const float4 b2 = s_acc[sub][64 + t];
        const float4 b3 = s_acc[sub][96 + t];
        float4 r;
        r.x = (b0.x + b1.x + b2.x + b3.x) * (1.0f / KK);
        r.y = (b0.y + b1.y + b2.y + b3.y) * (1.0f / KK);
        r.z = (b0.z + b1.z + b2.z + b3.z) * (1.0f / KK);
        r.w = (b0.w + b1.w + b2.w + b3.w) * (1.0f / KK);
        *(float4*)(os + (size_t)n * DD + 4 * t) = r;
    }
}

extern "C" void kernel_launch(void* const* d_in, const int* in_sizes, int n_in,
                              void* d_out, int out_size, void* d_ws, size_t ws_size,
                              hipStream_t stream) {
    const float* x1   = (const float*)d_in[0];
    const int*   idx1 = (const int*)  d_in[1];
    const float* dm1  = (const float*)d_in[2];
    const float* x2   = (const float*)d_in[3];
    const int*   idx2 = (const int*)  d_in[4];
    const float* dm2  = (const float*)d_in[5];
    const float* w    = (const float*)d_in[6];
    const float* b    = (const float*)d_in[7];
    float* out = (float*)d_out;

    const size_t need = (size_t)2 * NN * DD                   // x8: 8.39 MB
                      + (size_t)2 * NN * sizeof(float);       // xw: 0.26 MB
    if (ws_size >= need) {
        unsigned int* x8 = (unsigned int*)d_ws;
        float*        xw = (float*)((char*)d_ws + (size_t)2 * NN * DD);
        prep_kernel<<<dim3(2 * NN / 8), dim3(256), 0, stream>>>(x1, x2, w, x8, xw);
        pgnn_main<<<dim3(2 * NN / 16), dim3(256), 0, stream>>>(
            (const uint2*)x8, xw, idx1, dm1, idx2, dm2, b, out);
    } else {
        pgnn_fused<<<dim3(NN / 2, 2), dim3(256), 0, stream>>>(
            x1, idx1, dm1, x2, idx2, dm2, w, b, out);
    }
}